// Round 4
// baseline (108.347 us; speedup 1.0000x reference)
//
#include <hip/hip_runtime.h>
#include <hip/hip_bf16.h>
#include <stdint.h>

typedef float  f32x4   __attribute__((ext_vector_type(4)));
typedef float  f32x16  __attribute__((ext_vector_type(16)));
typedef __bf16 bf16x8  __attribute__((ext_vector_type(8)));
typedef __bf16 bf16x4  __attribute__((ext_vector_type(4)));
typedef uint32_t u32x4 __attribute__((ext_vector_type(4)));

#define LOG2E 1.44269504088896340736f

__device__ __forceinline__ f32x4 mfma16(bf16x8 a, bf16x8 b, f32x4 c) {
    return __builtin_amdgcn_mfma_f32_16x16x32_bf16(a, b, c, 0, 0, 0);
}
__device__ __forceinline__ f32x16 mfma32(bf16x8 a, bf16x8 b, f32x16 c) {
    return __builtin_amdgcn_mfma_f32_32x32x16_bf16(a, b, c, 0, 0, 0);
}

__device__ __forceinline__ float fast_exp2(float x) {
#if __has_builtin(__builtin_amdgcn_exp2f)
    return __builtin_amdgcn_exp2f(x);
#else
    return exp2f(x);
#endif
}

// packed f32x2 -> bf16x2 (RNE); D = {hi:bf16(s1), lo:bf16(s0)}
__device__ __forceinline__ uint32_t cvt_pk_bf16(float lo, float hi) {
    uint32_t r;
    asm("v_cvt_pk_bf16_f32 %0, %1, %2" : "=v"(r) : "v"(lo), "v"(hi));
    return r;
}
// D[lanes 32..63] <-> S[lanes 0..31]; both operands modified
__device__ __forceinline__ void perm32swap(uint32_t& a, uint32_t& b) {
    asm("v_permlane32_swap_b32 %0, %1" : "+v"(a), "+v"(b));
}

// async global->LDS, 16B per lane (wave-uniform base + lane*16 dest).
__device__ __forceinline__ void gload16(const void* g, void* lds) {
    __builtin_amdgcn_global_load_lds(
        (const __attribute__((address_space(1))) uint32_t*)g,
        (__attribute__((address_space(3))) uint32_t*)lds, 16, 0, 0);
}

// ---------------- fused cast(hs)+avgpool: one read of hs ----------------
__global__ void cast_pool_kernel(const float* __restrict__ hs,
                                 __bf16* __restrict__ hsb,
                                 __bf16* __restrict__ poolb, int n) {
    int i = blockIdx.x * blockDim.x + threadIdx.x;
    if (i >= n) return;
    int j = i >> 7;
    int c = (i & 127) * 8;
    int b = j >> 10, t = j & 1023;
    size_t rowg = (size_t)(b * 4096 + t * 4);
    const float* base = hs + (rowg << 10) + c;
    float sum[8];
#pragma unroll
    for (int e = 0; e < 8; ++e) sum[e] = 0.f;
#pragma unroll
    for (int r = 0; r < 4; ++r) {
        float4 a = *(const float4*)(base + (size_t)r * 1024);
        float4 d = *(const float4*)(base + (size_t)r * 1024 + 4);
        bf16x8 o;
        o[0] = (__bf16)a.x; o[1] = (__bf16)a.y; o[2] = (__bf16)a.z; o[3] = (__bf16)a.w;
        o[4] = (__bf16)d.x; o[5] = (__bf16)d.y; o[6] = (__bf16)d.z; o[7] = (__bf16)d.w;
        *reinterpret_cast<bf16x8*>(hsb + ((rowg + r) << 10) + c) = o;
        sum[0] += a.x; sum[1] += a.y; sum[2] += a.z; sum[3] += a.w;
        sum[4] += d.x; sum[5] += d.y; sum[6] += d.z; sum[7] += d.w;
    }
    bf16x8 p;
#pragma unroll
    for (int e = 0; e < 8; ++e) p[e] = (__bf16)(sum[e] * 0.25f);
    *reinterpret_cast<bf16x8*>(poolb + ((size_t)j << 10) + c) = p;
}

// ---------------- all three weight casts in one launch ----------------
__global__ void cast_w_kernel(const float* __restrict__ Wq, const float* __restrict__ Wk,
                              const float* __restrict__ Wv, __bf16* __restrict__ wqb,
                              __bf16* __restrict__ wkvb, float qscale, int n) {
    int i = blockIdx.x * blockDim.x + threadIdx.x;
    if (i >= n) return;
    const float* src; __bf16* dst; float sc; int j;
    if (i < 131072)      { src = Wq; dst = wqb;            sc = qscale; j = i; }
    else if (i < 262144) { src = Wk; dst = wkvb;           sc = 1.f;    j = i - 131072; }
    else                 { src = Wv; dst = wkvb + 1048576; sc = 1.f;    j = i - 262144; }
    const float4* s = reinterpret_cast<const float4*>(src) + (size_t)j * 2;
    float4 a = s[0], b = s[1];
    bf16x8 o;
    o[0] = (__bf16)(a.x * sc); o[1] = (__bf16)(a.y * sc);
    o[2] = (__bf16)(a.z * sc); o[3] = (__bf16)(a.w * sc);
    o[4] = (__bf16)(b.x * sc); o[5] = (__bf16)(b.y * sc);
    o[6] = (__bf16)(b.z * sc); o[7] = (__bf16)(b.w * sc);
    *reinterpret_cast<bf16x8*>(dst + (size_t)j * 8) = o;
}

// ---------------- pooled mask -> additive log2-domain bias ----------------
__global__ void mask_kernel(const int* __restrict__ mask,
                            float* __restrict__ mb, int n) {
    int i = blockIdx.x * blockDim.x + threadIdx.x;
    if (i >= n) return;
    int b = i >> 10, j = i & 1023;
    const int* p = mask + b * 4096 + j * 4;
    int any = p[0] | p[1] | p[2] | p[3];
    mb[i] = any ? (-10000.0f * LOG2E) : 0.0f;
}

// ---------------- fused Q + KV GEMM (unchanged from round 3) ----------------
__global__ __launch_bounds__(256)
void gemm_fused(const __bf16* __restrict__ hsb, const __bf16* __restrict__ poolb,
                const __bf16* __restrict__ wqb, const __bf16* __restrict__ wkvb,
                const float* __restrict__ bq, const float* __restrict__ bk,
                const float* __restrict__ bv, float qscale,
                __bf16* __restrict__ qb, __bf16* __restrict__ kb,
                __bf16* __restrict__ vtb) {
    __shared__ __bf16 As[128 * 64];
    __shared__ __bf16 Bs[128 * 64];
    const int tid  = threadIdx.x;
    const int lane = tid & 63, wid = tid >> 6;
    const int lg = lane >> 4, l15 = lane & 15;
    const int wm = (wid >> 1) * 64, wn = (wid & 1) * 64;

    const int id = blockIdx.x;
    const bool isQ = (id < 512);
    const int bx = isQ ? (id & 63) : ((id - 512) & 15);
    const int by = isQ ? (id >> 6) : ((id - 512) >> 4);
    const __bf16* A = isQ ? hsb : poolb;
    const __bf16* W = isQ ? wqb : wkvb;
    const int rowBase = bx * 128, colBase = by * 128;

    const f32x4 zero = {0.f, 0.f, 0.f, 0.f};
    f32x4 acc[4][4];
#pragma unroll
    for (int m = 0; m < 4; ++m)
#pragma unroll
        for (int n = 0; n < 4; ++n) acc[m][n] = zero;

    const char* Ag = (const char*)(A + (size_t)rowBase * 1024);
    const char* Wg = (const char*)(W + (size_t)colBase * 1024);
    char* AsB = (char*)As;
    char* BsB = (char*)Bs;

    const char* ag[4]; const char* wg[4]; int ld[4];
#pragma unroll
    for (int p = 0; p < 4; ++p) {
        int o  = p * 4096 + tid * 16;
        int r  = o >> 7, cb = o & 127;
        int cs = cb ^ ((r & 7) << 4);
        ag[p] = Ag + (size_t)r * 2048 + cs;
        wg[p] = Wg + (size_t)r * 2048 + cs;
        ld[p] = o;
    }

    for (int kt = 0; kt < 16; ++kt) {
        const int k0b = kt * 128;
        __syncthreads();
#pragma unroll
        for (int p = 0; p < 4; ++p) {
            gload16(ag[p] + k0b, AsB + ld[p]);
            gload16(wg[p] + k0b, BsB + ld[p]);
        }
        __syncthreads();

        bf16x8 af[4][2], bfr[4][2];
#pragma unroll
        for (int m = 0; m < 4; ++m)
#pragma unroll
            for (int kk = 0; kk < 2; ++kk) {
                int r  = wm + m * 16 + l15;
                int cb = kk * 64 + lg * 16;
                af[m][kk] = *(const bf16x8*)(AsB + r * 128 + (cb ^ ((r & 7) << 4)));
            }
#pragma unroll
        for (int n = 0; n < 4; ++n)
#pragma unroll
            for (int kk = 0; kk < 2; ++kk) {
                int r  = wn + n * 16 + l15;
                int cb = kk * 64 + lg * 16;
                bfr[n][kk] = *(const bf16x8*)(BsB + r * 128 + (cb ^ ((r & 7) << 4)));
            }
#pragma unroll
        for (int m = 0; m < 4; ++m)
#pragma unroll
            for (int n = 0; n < 4; ++n) {
                acc[m][n] = mfma16(af[m][0], bfr[n][0], acc[m][n]);
                acc[m][n] = mfma16(af[m][1], bfr[n][1], acc[m][n]);
            }
    }

#pragma unroll
    for (int m = 0; m < 4; ++m)
#pragma unroll
        for (int n = 0; n < 4; ++n) {
            int col  = colBase + wn + n * 16 + l15;
            int row0 = rowBase + wm + m * 16 + lg * 4;
            if (isQ) {
                float bvl = bq[col] * qscale;
#pragma unroll
                for (int reg = 0; reg < 4; ++reg)
                    qb[(size_t)(row0 + reg) * 1024 + col] = (__bf16)(acc[m][n][reg] + bvl);
            } else if (col < 1024) {
                float bvl = bk[col];
#pragma unroll
                for (int reg = 0; reg < 4; ++reg)
                    kb[(size_t)(row0 + reg) * 1024 + col] = (__bf16)(acc[m][n][reg] + bvl);
            } else {
                float bvl = bv[col - 1024];
                int bb   = row0 >> 10;
                int key0 = row0 & 1023;
                bf16x4 o;
#pragma unroll
                for (int reg = 0; reg < 4; ++reg) o[reg] = (__bf16)(acc[m][n][reg] + bvl);
                *reinterpret_cast<bf16x4*>(vtb + (((size_t)(bb * 1024 + (col - 1024))) << 10) + key0) = o;
            }
        }
}

// ---------------- flash attention: 32x32x16 MFMA, in-register P via cvt_pk+permlane ----------------
// Per block: 4 waves x 64 q rows = 256 q. KV tiles of 64 keys, double-buffered.
// Swapped QK^T: S^T col=q=lane&31, row=key=(reg&3)+8*(reg>>2)+4*hi.
// P A-frag (row=q, k=key=hi*8+j) built with 8 cvt_pk + 4 permlane32_swap per 32x32 tile.
__global__ __launch_bounds__(256, 2)
void attn_kernel(const __bf16* __restrict__ Q, const __bf16* __restrict__ K,
                 const __bf16* __restrict__ Vt, const float* __restrict__ mb,
                 float* __restrict__ out) {
    __shared__ __bf16 Ks[2][64 * 64];
    __shared__ __bf16 Vs[2][64 * 64];
    const int tid  = threadIdx.x;
    const int lane = tid & 63, wid = tid >> 6;
    const int l31 = lane & 31, hi = lane >> 5;

    // XCD-aware bijective swizzle (512 blocks, 64 consecutive per XCD)
    const int lin = blockIdx.x + blockIdx.y * 16;
    const int nid = (lin & 7) * 64 + (lin >> 3);
    const int qi = nid & 15, bh = nid >> 4;
    const int b = bh >> 4, h = bh & 15;
    const int qbase = qi * 256 + wid * 64;

    // Q B-frags: [qt][ds], col=q=l31, k(hi*8+j) at d = ds*16+hi*8
    bf16x8 qf[2][4];
#pragma unroll
    for (int qt = 0; qt < 2; ++qt)
#pragma unroll
        for (int ds = 0; ds < 4; ++ds)
            qf[qt][ds] = *(const bf16x8*)(Q + (((size_t)(b * 4096 + qbase + qt * 32 + l31)) << 10)
                                          + h * 64 + ds * 16 + hi * 8);

    f32x16 acc[2][2];
#pragma unroll
    for (int qt = 0; qt < 2; ++qt)
#pragma unroll
        for (int dt = 0; dt < 2; ++dt)
#pragma unroll
            for (int r = 0; r < 16; ++r) acc[qt][dt][r] = 0.f;
    float rs[2] = {0.f, 0.f};

    const char* Kg = (const char*)(K + (((size_t)(b * 1024)) << 10) + h * 64);
    const char* Vg = (const char*)(Vt + (((size_t)(b * 1024 + h * 64)) << 10));
    const float* mbp = mb + b * 1024;

    const char* kg[2]; const char* vg[2]; int ld[2];
#pragma unroll
    for (int p = 0; p < 2; ++p) {
        int o  = p * 4096 + tid * 16;
        int r  = o >> 7, cb = o & 127;
        int cs = cb ^ ((r & 7) << 4);
        kg[p] = Kg + (size_t)r * 2048 + cs;
        vg[p] = Vg + (size_t)r * 2048 + cs;
        ld[p] = o;
    }

#pragma unroll
    for (int p = 0; p < 2; ++p) {
        gload16(kg[p], (char*)Ks[0] + ld[p]);
        gload16(vg[p], (char*)Vs[0] + ld[p]);
    }

    int cur = 0;
    for (int kt = 0; kt < 16; ++kt) {
        __syncthreads();   // buf[cur] ready (vmcnt drained at barrier), buf[cur^1] free
        if (kt < 15) {
#pragma unroll
            for (int p = 0; p < 2; ++p) {
                gload16(kg[p] + (size_t)(kt + 1) * 131072, (char*)Ks[cur ^ 1] + ld[p]);
                gload16(vg[p] + (kt + 1) * 128,            (char*)Vs[cur ^ 1] + ld[p]);
            }
        }
        const char* KsB = (const char*)Ks[cur];
        const char* VsB = (const char*)Vs[cur];

        // K A-frags: row=key=nt*32+l31, k at d=ds*16+hi*8  (reused across both qt)
        bf16x8 kf[2][4];
#pragma unroll
        for (int nt = 0; nt < 2; ++nt)
#pragma unroll
            for (int ds = 0; ds < 4; ++ds) {
                int row = nt * 32 + l31;
                kf[nt][ds] = *(const bf16x8*)(KsB + row * 128 + ((ds * 32 + hi * 16) ^ ((row & 7) << 4)));
            }

        u32x4 pf[2][4];   // P A-frags per qt, 4 key-slices of 16
#pragma unroll
        for (int qt = 0; qt < 2; ++qt) {
#pragma unroll
            for (int nt = 0; nt < 2; ++nt) {
                f32x16 s;
#pragma unroll
                for (int r = 0; r < 16; ++r) s[r] = 0.f;
#pragma unroll
                for (int ds = 0; ds < 4; ++ds) s = mfma32(kf[nt][ds], qf[qt][ds], s);

                // mask per reg r: key = nt*32 + (r>>2)*8 + (r&3) + 4*hi
                const float* mbase = mbp + kt * 64 + nt * 32 + hi * 4;
                float p[16];
#pragma unroll
                for (int i = 0; i < 4; ++i) {
                    float4 mv = *(const float4*)(mbase + i * 8);
                    p[i * 4 + 0] = fast_exp2(s[i * 4 + 0] + mv.x);
                    p[i * 4 + 1] = fast_exp2(s[i * 4 + 1] + mv.y);
                    p[i * 4 + 2] = fast_exp2(s[i * 4 + 2] + mv.z);
                    p[i * 4 + 3] = fast_exp2(s[i * 4 + 3] + mv.w);
                }
                float t0 = (p[0] + p[1]) + (p[2] + p[3]);
                float t1 = (p[4] + p[5]) + (p[6] + p[7]);
                float t2 = (p[8] + p[9]) + (p[10] + p[11]);
                float t3 = (p[12] + p[13]) + (p[14] + p[15]);
                rs[qt] += (t0 + t1) + (t2 + t3);

                // pack pairs: c[i] = keys(2i,2i+1)+4hi of this nt-tile
                uint32_t c0 = cvt_pk_bf16(p[0], p[1]),   c1 = cvt_pk_bf16(p[2], p[3]);
                uint32_t c2 = cvt_pk_bf16(p[4], p[5]),   c3 = cvt_pk_bf16(p[6], p[7]);
                uint32_t c4 = cvt_pk_bf16(p[8], p[9]),   c5 = cvt_pk_bf16(p[10], p[11]);
                uint32_t c6 = cvt_pk_bf16(p[12], p[13]), c7 = cvt_pk_bf16(p[14], p[15]);
                // redistribute halves: after swap, (c0,c1,c2,c3) = keys slice nt*2+0,
                // (c4,c5,c6,c7) = keys slice nt*2+1 in A-frag order
                perm32swap(c0, c2); perm32swap(c1, c3);
                perm32swap(c4, c6); perm32swap(c5, c7);
                u32x4 lo4 = {c0, c1, c2, c3};
                u32x4 hi4 = {c4, c5, c6, c7};
                pf[qt][nt * 2 + 0] = lo4;
                pf[qt][nt * 2 + 1] = hi4;
            }
        }

        // PV: acc[qt][dt] += P[qt][ks] x V[ks][dt]   (V B-frag: col=d=l31, k=key)
#pragma unroll
        for (int dt = 0; dt < 2; ++dt)
#pragma unroll
            for (int ks = 0; ks < 4; ++ks) {
                int row = dt * 32 + l31;
                bf16x8 vb = *(const bf16x8*)(VsB + row * 128 + ((ks * 32 + hi * 16) ^ ((row & 7) << 4)));
#pragma unroll
                for (int qt = 0; qt < 2; ++qt)
                    acc[qt][dt] = mfma32(__builtin_bit_cast(bf16x8, pf[qt][ks]), vb, acc[qt][dt]);
            }
        cur ^= 1;
    }

    // final row sums: lanes q and q+32 hold partials for q = l31
#pragma unroll
    for (int qt = 0; qt < 2; ++qt) rs[qt] += __shfl_xor(rs[qt], 32);

    // epilogue: out row q = (r&3)+8*(r>>2)+4*hi, col = dt*32 + l31 (coalesced 128B)
#pragma unroll
    for (int qt = 0; qt < 2; ++qt)
#pragma unroll
        for (int r = 0; r < 16; ++r) {
            int ql = (r & 3) + 8 * (r >> 2) + 4 * hi;
            float inv = 1.0f / __shfl(rs[qt], ql);
            size_t row = (size_t)(b * 4096 + qbase + qt * 32 + ql);
#pragma unroll
            for (int dt = 0; dt < 2; ++dt)
                out[(row << 10) + h * 64 + dt * 32 + l31] = acc[qt][dt][r] * inv;
        }
}

extern "C" void kernel_launch(void* const* d_in, const int* in_sizes, int n_in,
                              void* d_out, int out_size, void* d_ws, size_t ws_size,
                              hipStream_t stream) {
    const float* hs    = (const float*)d_in[0];
    const int*   amask = (const int*)d_in[1];
    const float* Wq    = (const float*)d_in[2];
    const float* bq    = (const float*)d_in[3];
    const float* Wk    = (const float*)d_in[4];
    const float* bk    = (const float*)d_in[5];
    const float* Wv    = (const float*)d_in[6];
    const float* bv    = (const float*)d_in[7];
    float* out = (float*)d_out;

    char* ws = (char*)d_ws;
    size_t off = 0;
    auto alloc = [&](size_t bytes) -> char* {
        char* p = ws + off;
        off += (bytes + 255) & ~(size_t)255;
        return p;
    };
    __bf16* hsb   = (__bf16*)alloc(8388608ull * 2);  // hidden bf16 [8192][1024]
    __bf16* qb    = (__bf16*)alloc(8388608ull * 2);  // Q bf16 (pre-scaled)
    __bf16* poolb = (__bf16*)alloc(2097152ull * 2);  // pooled bf16 [2048][1024]
    __bf16* kb    = (__bf16*)alloc(2097152ull * 2);  // K bf16
    __bf16* vtb   = (__bf16*)alloc(2097152ull * 2);  // V^T bf16 [b,h,d][key]
    __bf16* wqb   = (__bf16*)alloc(1048576ull * 2);  // Wq * qscale
    __bf16* wkvb  = (__bf16*)alloc(2097152ull * 2);  // [Wk ; Wv]
    float*  mbf   = (float*)alloc(2048 * 4);

    const float qscale = 0.125f * LOG2E;   // 1/sqrt(DH) and log2(e) folded into Q

    cast_pool_kernel<<<1024, 256, 0, stream>>>(hs, hsb, poolb, 262144);
    cast_w_kernel<<<1536, 256, 0, stream>>>(Wq, Wk, Wv, wqb, wkvb, qscale, 393216);
    mask_kernel<<<8, 256, 0, stream>>>(amask, mbf, 2048);

    gemm_fused<<<768, 256, 0, stream>>>(hsb, poolb, wqb, wkvb, bq, bk, bv, qscale,
                                        qb, kb, vtb);

    attn_kernel<<<dim3(16, 32), 256, 0, stream>>>(qb, kb, vtb, mbf, out);
}